// Round 12
// baseline (690.818 us; speedup 1.0000x reference)
//
#include <hip/hip_runtime.h>

#define NN 50000
#define DD 256
#define NT 3
#define NL 4
#define EPT 300000
#define KK 768           // 3*DD concatenated-K
#define SCAN_BLOCKS 196  // ceil(50000/256)
#define MROWS 50048      // Gcat rows padded to 64/128 multiples

typedef __attribute__((ext_vector_type(8))) short bf16x8;
typedef __attribute__((ext_vector_type(4))) float f32x4;
typedef __attribute__((ext_vector_type(4))) unsigned int u32x4;
typedef __attribute__((ext_vector_type(2))) unsigned int u32x2;

__device__ __forceinline__ unsigned short f2bf(float f) {
  unsigned u = __builtin_bit_cast(unsigned, f);
  unsigned r = u + 0x7fffu + ((u >> 16) & 1u);  // RNE
  return (unsigned short)(r >> 16);
}
__device__ __forceinline__ float bflo2f(unsigned u) {
  return __builtin_bit_cast(float, u << 16);
}
__device__ __forceinline__ float bfhi2f(unsigned u) {
  return __builtin_bit_cast(float, u & 0xffff0000u);
}

// ---------------- h0[i] = bf16(emb[labels[i]]) ----------------
__global__ void gather_emb(const int* __restrict__ labels,
                           const float* __restrict__ emb,
                           unsigned short* __restrict__ h) {
  int node = blockIdx.x;
  int lane = threadIdx.x;  // 0..63
  float4 v = ((const float4*)(emb + (size_t)labels[node] * DD))[lane];
  unsigned a = (unsigned)f2bf(v.x) | ((unsigned)f2bf(v.y) << 16);
  unsigned b = (unsigned)f2bf(v.z) | ((unsigned)f2bf(v.w) << 16);
  ((uint2*)(h + (size_t)node * DD))[lane] = make_uint2(a, b);
}

// ---------------- zero buffer ----------------
__global__ void zero_kernel(float* __restrict__ p, int n4) {
  int i = blockIdx.x * blockDim.x + threadIdx.x;
  int stride = gridDim.x * blockDim.x;
  float4* p4 = (float4*)p;
  for (; i < n4; i += stride) p4[i] = make_float4(0.f, 0.f, 0.f, 0.f);
}

// ---------------- W -> bf16, transposed+concatenated: WT[l][n][t*256+k] ----------------
__global__ __launch_bounds__(256) void wconv(const float* __restrict__ Wl,
                                             unsigned short* __restrict__ WT) {
  int i = blockIdx.x * 256 + threadIdx.x;
  int l = i / (DD * KK);
  int rem = i % (DD * KK);
  int n = rem / KK;
  int kk = rem % KK;
  int t = kk >> 8;
  int k = kk & 255;
  float v = Wl[((size_t)(l * NT + t) * DD + k) * DD + n];
  WT[i] = f2bf(v);
}

// ---------------- CSR build ----------------
__global__ __launch_bounds__(256) void hist_kernel(const int* __restrict__ adj,
                                                   int* __restrict__ counts) {
  int t = blockIdx.y;
  int e = blockIdx.x * 256 + threadIdx.x;
  if (e >= EPT) return;
  int tgt = adj[(size_t)t * EPT * 2 + 2 * e + 1];
  atomicAdd(&counts[t * NN + tgt], 1);
}

__global__ __launch_bounds__(256) void scan1(const int* __restrict__ counts,
                                             int* __restrict__ rowptr,
                                             int* __restrict__ bsums) {
  int t = blockIdx.y, b = blockIdx.x;
  int i = b * 256 + threadIdx.x;
  int v = (i < NN) ? counts[t * NN + i] : 0;
  __shared__ int s[256];
  s[threadIdx.x] = v;
  __syncthreads();
  for (int off = 1; off < 256; off <<= 1) {
    int y = (threadIdx.x >= off) ? s[threadIdx.x - off] : 0;
    __syncthreads();
    s[threadIdx.x] += y;
    __syncthreads();
  }
  if (i < NN) rowptr[t * (NN + 1) + i] = s[threadIdx.x] - v;  // exclusive
  if (threadIdx.x == 255) bsums[t * SCAN_BLOCKS + b] = s[255];
}

__global__ __launch_bounds__(256) void scan2(int* __restrict__ bsums) {
  int t = blockIdx.x;
  int v = (threadIdx.x < SCAN_BLOCKS) ? bsums[t * SCAN_BLOCKS + threadIdx.x] : 0;
  __shared__ int s[256];
  s[threadIdx.x] = v;
  __syncthreads();
  for (int off = 1; off < 256; off <<= 1) {
    int y = (threadIdx.x >= off) ? s[threadIdx.x - off] : 0;
    __syncthreads();
    s[threadIdx.x] += y;
    __syncthreads();
  }
  if (threadIdx.x < SCAN_BLOCKS) bsums[t * SCAN_BLOCKS + threadIdx.x] = s[threadIdx.x] - v;
}

__global__ __launch_bounds__(256) void scan3(int* __restrict__ rowptr,
                                             const int* __restrict__ bsums,
                                             int* __restrict__ cursor) {
  int t = blockIdx.y, b = blockIdx.x;
  int i = b * 256 + threadIdx.x;
  if (i < NN) {
    int r = rowptr[t * (NN + 1) + i] + bsums[t * SCAN_BLOCKS + b];
    rowptr[t * (NN + 1) + i] = r;
    cursor[t * NN + i] = r;
  }
  if (b == 0 && threadIdx.x == 0) rowptr[t * (NN + 1) + NN] = EPT;
}

__global__ __launch_bounds__(256) void bucket_kernel(const int* __restrict__ adj,
                                                     int* __restrict__ cursor,
                                                     int* __restrict__ esrc) {
  int t = blockIdx.y;
  int e = blockIdx.x * 256 + threadIdx.x;
  if (e >= EPT) return;
  int s = adj[(size_t)t * EPT * 2 + 2 * e];
  int tgt = adj[(size_t)t * EPT * 2 + 2 * e + 1];
  int pos = atomicAdd(&cursor[t * NN + tgt], 1);
  esrc[(size_t)t * EPT + pos] = s;
}

// ---------------- agg: Gcat[n][t*256..] = bf16( sum_{e in(n)} h[src(e)] ) ----------------
// ONE node per wave: 64 lanes x uint2(8B) = one 512B row; unroll 4; no divergence.
__global__ __launch_bounds__(256) void agg_csr(const int* __restrict__ rowptr,
                                               const int* __restrict__ esrc,
                                               const unsigned short* __restrict__ h,
                                               unsigned short* __restrict__ Gcat) {
  int t = blockIdx.y;
  int node = blockIdx.x * 4 + (threadIdx.x >> 6);
  if (node >= NN) return;
  int lane = threadIdx.x & 63;
  const int* rp = rowptr + t * (NN + 1);
  const int* es = esrc + (size_t)t * EPT;
  int e = rp[node];
  int end = rp[node + 1];
  const u32x2* h2 = (const u32x2*)h;
  float a0 = 0.f, a1 = 0.f, a2 = 0.f, a3 = 0.f;
  for (; e + 3 < end; e += 4) {
    u32x2 v0 = h2[(size_t)es[e] * 64 + lane];
    u32x2 v1 = h2[(size_t)es[e + 1] * 64 + lane];
    u32x2 v2 = h2[(size_t)es[e + 2] * 64 + lane];
    u32x2 v3 = h2[(size_t)es[e + 3] * 64 + lane];
    a0 += (bflo2f(v0.x) + bflo2f(v1.x)) + (bflo2f(v2.x) + bflo2f(v3.x));
    a1 += (bfhi2f(v0.x) + bfhi2f(v1.x)) + (bfhi2f(v2.x) + bfhi2f(v3.x));
    a2 += (bflo2f(v0.y) + bflo2f(v1.y)) + (bflo2f(v2.y) + bflo2f(v3.y));
    a3 += (bfhi2f(v0.y) + bfhi2f(v1.y)) + (bfhi2f(v2.y) + bfhi2f(v3.y));
  }
  for (; e < end; ++e) {
    u32x2 v0 = h2[(size_t)es[e] * 64 + lane];
    a0 += bflo2f(v0.x);
    a1 += bfhi2f(v0.x);
    a2 += bflo2f(v0.y);
    a3 += bfhi2f(v0.y);
  }
  u32x2 o;
  o.x = (unsigned)f2bf(a0) | ((unsigned)f2bf(a1) << 16);
  o.y = (unsigned)f2bf(a2) | ((unsigned)f2bf(a3) << 16);
  ((u32x2*)(Gcat + (size_t)node * KK + t * DD))[lane] = o;
}

// ---------------- bf16 MFMA GEMM: C = relu(Gcat[M][768] @ WT^T), N=256 ----------------
// BM=64, BN=256 (A read ONCE), 256 threads = 4 waves, each a 64x64 wave tile.
// 782 blocks (~3/CU = 3 barrier domains). LDS 40KB (A 8KB | B 32KB), XOR-swizzled;
// reg-prefetch next kt before compute; 2 barriers per kt (r10/r11-proven loop).
template <int OUTF32>
__global__ __launch_bounds__(256) void gemm_bf16(const unsigned short* __restrict__ A,
                                                 const unsigned short* __restrict__ BT,
                                                 void* __restrict__ Cout) {
  __shared__ __align__(16) char lds[40960];  // [A 8KB | B 32KB]
  const int tid = threadIdx.x;
  const int w = tid >> 6, lane = tid & 63;
  const int m0 = blockIdx.x * 64;
  const int wn = w * 64;
  const int r15 = lane & 15;
  const int g16 = (lane >> 4) * 16;  // byte offset of k-subgroup (8 bf16)

  f32x4 acc[4][4] = {};
  const char* Ab = (const char*)A;
  const char* Bb = (const char*)BT;

  // A staging: 256 thr x 32B: arow = tid>>2 (0..63), acol = (tid&3)*32
  const int arow = tid >> 2;
  const int acol = (tid & 3) * 32;
  const int asw = (arow & 7) << 4;
  // B staging: 256 thr x 128B: brow = tid (0..255), full row of the k-tile
  const int brow = tid;
  const int bsw = (brow & 7) << 4;
  u32x4 ra[2], rb[8];

  const int NTK = KK / 64;  // 12

#define GLOAD(kt)                                                            \
  {                                                                          \
    const char* ap = Ab + (size_t)(m0 + arow) * (KK * 2) + (size_t)(kt)*128; \
    const char* bp = Bb + (size_t)brow * (KK * 2) + (size_t)(kt)*128;        \
    ra[0] = *(const u32x4*)(ap + acol);                                      \
    ra[1] = *(const u32x4*)(ap + acol + 16);                                 \
    _Pragma("unroll") for (int p = 0; p < 8; p++) rb[p] =                    \
        *(const u32x4*)(bp + p * 16);                                        \
  }
#define SWRITE()                                                             \
  {                                                                          \
    *(u32x4*)(lds + arow * 128 + (acol ^ asw)) = ra[0];                      \
    *(u32x4*)(lds + arow * 128 + ((acol + 16) ^ asw)) = ra[1];               \
    _Pragma("unroll") for (int p = 0; p < 8; p++) *(u32x4*)(                 \
        lds + 8192 + brow * 128 + ((p * 16) ^ bsw)) = rb[p];                 \
  }

  GLOAD(0);
  SWRITE();
  __syncthreads();
  for (int kt = 0; kt < NTK; ++kt) {
    if (kt + 1 < NTK) GLOAD(kt + 1);  // issue next-tile loads before compute
#pragma unroll
    for (int ks = 0; ks < 2; ++ks) {
      bf16x8 af[4], bfr[4];
#pragma unroll
      for (int mf = 0; mf < 4; ++mf) {
        int row = mf * 16 + r15;
        af[mf] = *(const bf16x8*)(lds + row * 128 + ((ks * 64 + g16) ^ ((row & 7) << 4)));
      }
#pragma unroll
      for (int nf = 0; nf < 4; ++nf) {
        int row = wn + nf * 16 + r15;
        bfr[nf] =
            *(const bf16x8*)(lds + 8192 + row * 128 + ((ks * 64 + g16) ^ ((row & 7) << 4)));
      }
#pragma unroll
      for (int mf = 0; mf < 4; ++mf)
#pragma unroll
        for (int nf = 0; nf < 4; ++nf)
          acc[mf][nf] =
              __builtin_amdgcn_mfma_f32_16x16x32_bf16(af[mf], bfr[nf], acc[mf][nf], 0, 0, 0);
    }
    if (kt + 1 < NTK) {
      __syncthreads();  // all waves done reading this tile
      SWRITE();         // overwrite with prefetched next tile
      __syncthreads();  // writes visible
    }
  }

  // epilogue: D row = (lane>>4)*4 + reg, col = lane&15 (verified m89 layout); ReLU
#pragma unroll
  for (int mf = 0; mf < 4; ++mf) {
#pragma unroll
    for (int r = 0; r < 4; ++r) {
      int grow = m0 + mf * 16 + (lane >> 4) * 4 + r;
      if (grow >= NN) continue;
#pragma unroll
      for (int nf = 0; nf < 4; ++nf) {
        int gcol = wn + nf * 16 + r15;
        float v = fmaxf(acc[mf][nf][r], 0.f);
        if (OUTF32)
          ((float*)Cout)[(size_t)grow * DD + gcol] = v;
        else
          ((unsigned short*)Cout)[(size_t)grow * DD + gcol] = f2bf(v);
      }
    }
  }
#undef GLOAD
#undef SWRITE
}

extern "C" void kernel_launch(void* const* d_in, const int* in_sizes, int n_in,
                              void* d_out, int out_size, void* d_ws, size_t ws_size,
                              hipStream_t stream) {
  const int* labels = (const int*)d_in[0];
  const int* adj = (const int*)d_in[1];      // [NT][EPT][2]
  const float* emb = (const float*)d_in[2];  // [VOCAB][DD]
  const float* Wl = (const float*)d_in[3];   // [NL][NT][DD][DD]

  // ---- workspace layout (~108.3 MB) ----
  char* base = (char*)d_ws;
  unsigned short* h = (unsigned short*)base;  // bf16 [NN][256], 25.6 MB
  size_t off = (size_t)NN * DD * 2;
  unsigned short* Gcat = (unsigned short*)(base + off);  // bf16 [MROWS][768], 76.9 MB
  off += (size_t)MROWS * KK * 2;
  unsigned short* WT = (unsigned short*)(base + off);  // bf16 [NL][256][768], 1.57 MB
  off += (size_t)NL * DD * KK * 2;
  int* rowptr = (int*)(base + off);  // [NT][NN+1]
  off += (size_t)((NT * (NN + 1) * 4 + 15) & ~15);
  int* esrc = (int*)(base + off);  // [NT][EPT]

  // CSR-build temporaries overlaid on Gcat (not live until first agg)
  int* counts = (int*)Gcat;                       // 3*NN ints
  int* cursor = (int*)((char*)Gcat + (1 << 20));  // +1MB
  int* bsums = (int*)((char*)Gcat + (2 << 20));   // +2MB

  // ---- weight convert + h0 gather ----
  wconv<<<(NL * DD * KK) / 256, 256, 0, stream>>>(Wl, WT);
  gather_emb<<<NN, 64, 0, stream>>>(labels, emb, h);

  // ---- CSR build (once; adjacency shared by all layers) ----
  zero_kernel<<<256, 256, 0, stream>>>((float*)counts, (3 * NN) / 4);
  {
    dim3 g((EPT + 255) / 256, NT);
    hist_kernel<<<g, 256, 0, stream>>>(adj, counts);
  }
  {
    dim3 g(SCAN_BLOCKS, NT);
    scan1<<<g, 256, 0, stream>>>(counts, rowptr, bsums);
  }
  scan2<<<NT, 256, 0, stream>>>(bsums);
  {
    dim3 g(SCAN_BLOCKS, NT);
    scan3<<<g, 256, 0, stream>>>(rowptr, bsums, cursor);
  }
  {
    dim3 g((EPT + 255) / 256, NT);
    bucket_kernel<<<g, 256, 0, stream>>>(adj, cursor, esrc);
  }

  // ---- layers: agg (all 3 types, one dispatch) then one K=768 GEMM ----
  dim3 ga((NN + 3) / 4, NT);
  const int gg = MROWS / 64;  // 782 blocks, full-N per block
  for (int l = 0; l < NL; ++l) {
    agg_csr<<<ga, 256, 0, stream>>>(rowptr, esrc, h, Gcat);
    const unsigned short* WTl = WT + (size_t)l * DD * KK;
    if (l < NL - 1)
      gemm_bf16<0><<<gg, 256, 0, stream>>>(Gcat, WTl, h);
    else
      gemm_bf16<1><<<gg, 256, 0, stream>>>(Gcat, WTl, d_out);
  }
}

// Round 13
// 517.710 us; speedup vs baseline: 1.3344x; 1.3344x over previous
//
#include <hip/hip_runtime.h>

#define NN 50000
#define DD 256
#define NT 3
#define NL 4
#define EPT 300000
#define KK 768           // 3*DD concatenated-K
#define SCAN_BLOCKS 196  // ceil(50000/256)
#define MROWS 50048      // Gcat rows padded to 128

typedef __attribute__((ext_vector_type(8))) short bf16x8;
typedef __attribute__((ext_vector_type(4))) float f32x4;
typedef __attribute__((ext_vector_type(4))) unsigned int u32x4;

__device__ __forceinline__ unsigned short f2bf(float f) {
  unsigned u = __builtin_bit_cast(unsigned, f);
  unsigned r = u + 0x7fffu + ((u >> 16) & 1u);  // RNE
  return (unsigned short)(r >> 16);
}
__device__ __forceinline__ float bflo2f(unsigned u) {
  return __builtin_bit_cast(float, u << 16);
}
__device__ __forceinline__ float bfhi2f(unsigned u) {
  return __builtin_bit_cast(float, u & 0xffff0000u);
}

// ---------------- h0[i] = bf16(emb[labels[i]]) ----------------
__global__ void gather_emb(const int* __restrict__ labels,
                           const float* __restrict__ emb,
                           unsigned short* __restrict__ h) {
  int node = blockIdx.x;
  int lane = threadIdx.x;  // 0..63
  float4 v = ((const float4*)(emb + (size_t)labels[node] * DD))[lane];
  unsigned a = (unsigned)f2bf(v.x) | ((unsigned)f2bf(v.y) << 16);
  unsigned b = (unsigned)f2bf(v.z) | ((unsigned)f2bf(v.w) << 16);
  ((uint2*)(h + (size_t)node * DD))[lane] = make_uint2(a, b);
}

// ---------------- zero buffer ----------------
__global__ void zero_kernel(float* __restrict__ p, int n4) {
  int i = blockIdx.x * blockDim.x + threadIdx.x;
  int stride = gridDim.x * blockDim.x;
  float4* p4 = (float4*)p;
  for (; i < n4; i += stride) p4[i] = make_float4(0.f, 0.f, 0.f, 0.f);
}

// ---------------- W -> bf16, transposed+concatenated: WT[l][n][t*256+k] ----------------
__global__ __launch_bounds__(256) void wconv(const float* __restrict__ Wl,
                                             unsigned short* __restrict__ WT) {
  int i = blockIdx.x * 256 + threadIdx.x;
  int l = i / (DD * KK);
  int rem = i % (DD * KK);
  int n = rem / KK;
  int kk = rem % KK;
  int t = kk >> 8;
  int k = kk & 255;
  float v = Wl[((size_t)(l * NT + t) * DD + k) * DD + n];
  WT[i] = f2bf(v);
}

// ---------------- CSR build ----------------
__global__ __launch_bounds__(256) void hist_kernel(const int* __restrict__ adj,
                                                   int* __restrict__ counts) {
  int t = blockIdx.y;
  int e = blockIdx.x * 256 + threadIdx.x;
  if (e >= EPT) return;
  int tgt = adj[(size_t)t * EPT * 2 + 2 * e + 1];
  atomicAdd(&counts[t * NN + tgt], 1);
}

__global__ __launch_bounds__(256) void scan1(const int* __restrict__ counts,
                                             int* __restrict__ rowptr,
                                             int* __restrict__ bsums) {
  int t = blockIdx.y, b = blockIdx.x;
  int i = b * 256 + threadIdx.x;
  int v = (i < NN) ? counts[t * NN + i] : 0;
  __shared__ int s[256];
  s[threadIdx.x] = v;
  __syncthreads();
  for (int off = 1; off < 256; off <<= 1) {
    int y = (threadIdx.x >= off) ? s[threadIdx.x - off] : 0;
    __syncthreads();
    s[threadIdx.x] += y;
    __syncthreads();
  }
  if (i < NN) rowptr[t * (NN + 1) + i] = s[threadIdx.x] - v;  // exclusive
  if (threadIdx.x == 255) bsums[t * SCAN_BLOCKS + b] = s[255];
}

__global__ __launch_bounds__(256) void scan2(int* __restrict__ bsums) {
  int t = blockIdx.x;
  int v = (threadIdx.x < SCAN_BLOCKS) ? bsums[t * SCAN_BLOCKS + threadIdx.x] : 0;
  __shared__ int s[256];
  s[threadIdx.x] = v;
  __syncthreads();
  for (int off = 1; off < 256; off <<= 1) {
    int y = (threadIdx.x >= off) ? s[threadIdx.x - off] : 0;
    __syncthreads();
    s[threadIdx.x] += y;
    __syncthreads();
  }
  if (threadIdx.x < SCAN_BLOCKS) bsums[t * SCAN_BLOCKS + threadIdx.x] = s[threadIdx.x] - v;
}

__global__ __launch_bounds__(256) void scan3(int* __restrict__ rowptr,
                                             const int* __restrict__ bsums,
                                             int* __restrict__ cursor) {
  int t = blockIdx.y, b = blockIdx.x;
  int i = b * 256 + threadIdx.x;
  if (i < NN) {
    int r = rowptr[t * (NN + 1) + i] + bsums[t * SCAN_BLOCKS + b];
    rowptr[t * (NN + 1) + i] = r;
    cursor[t * NN + i] = r;
  }
  if (b == 0 && threadIdx.x == 0) rowptr[t * (NN + 1) + NN] = EPT;
}

__global__ __launch_bounds__(256) void bucket_kernel(const int* __restrict__ adj,
                                                     int* __restrict__ cursor,
                                                     int* __restrict__ esrc) {
  int t = blockIdx.y;
  int e = blockIdx.x * 256 + threadIdx.x;
  if (e >= EPT) return;
  int s = adj[(size_t)t * EPT * 2 + 2 * e];
  int tgt = adj[(size_t)t * EPT * 2 + 2 * e + 1];
  int pos = atomicAdd(&cursor[t * NN + tgt], 1);
  esrc[(size_t)t * EPT + pos] = s;
}

// ---------------- agg: Gcat[n][t*256..] = bf16( sum_{e in(n)} h[src(e)] ) ----------------
// 2 nodes per wave: 32 lanes x 16B = one 512B row each; unroll 4 (r11-proven).
__global__ __launch_bounds__(256) void agg_csr(const int* __restrict__ rowptr,
                                               const int* __restrict__ esrc,
                                               const unsigned short* __restrict__ h,
                                               unsigned short* __restrict__ Gcat) {
  int t = blockIdx.y;
  int node = blockIdx.x * 8 + (threadIdx.x >> 5);
  if (node >= NN) return;
  int sub = threadIdx.x & 31;
  const int* rp = rowptr + t * (NN + 1);
  const int* es = esrc + (size_t)t * EPT;
  int e = rp[node];
  int end = rp[node + 1];
  const u32x4* h4 = (const u32x4*)h;
  float a0 = 0.f, a1 = 0.f, a2 = 0.f, a3 = 0.f, a4 = 0.f, a5 = 0.f, a6 = 0.f, a7 = 0.f;
  for (; e + 3 < end; e += 4) {
    u32x4 v0 = h4[(size_t)es[e] * 32 + sub];
    u32x4 v1 = h4[(size_t)es[e + 1] * 32 + sub];
    u32x4 v2 = h4[(size_t)es[e + 2] * 32 + sub];
    u32x4 v3 = h4[(size_t)es[e + 3] * 32 + sub];
    a0 += (bflo2f(v0.x) + bflo2f(v1.x)) + (bflo2f(v2.x) + bflo2f(v3.x));
    a1 += (bfhi2f(v0.x) + bfhi2f(v1.x)) + (bfhi2f(v2.x) + bfhi2f(v3.x));
    a2 += (bflo2f(v0.y) + bflo2f(v1.y)) + (bflo2f(v2.y) + bflo2f(v3.y));
    a3 += (bfhi2f(v0.y) + bfhi2f(v1.y)) + (bfhi2f(v2.y) + bfhi2f(v3.y));
    a4 += (bflo2f(v0.z) + bflo2f(v1.z)) + (bflo2f(v2.z) + bflo2f(v3.z));
    a5 += (bfhi2f(v0.z) + bfhi2f(v1.z)) + (bfhi2f(v2.z) + bfhi2f(v3.z));
    a6 += (bflo2f(v0.w) + bflo2f(v1.w)) + (bflo2f(v2.w) + bflo2f(v3.w));
    a7 += (bfhi2f(v0.w) + bfhi2f(v1.w)) + (bfhi2f(v2.w) + bfhi2f(v3.w));
  }
  for (; e < end; ++e) {
    u32x4 v0 = h4[(size_t)es[e] * 32 + sub];
    a0 += bflo2f(v0.x);
    a1 += bfhi2f(v0.x);
    a2 += bflo2f(v0.y);
    a3 += bfhi2f(v0.y);
    a4 += bflo2f(v0.z);
    a5 += bfhi2f(v0.z);
    a6 += bflo2f(v0.w);
    a7 += bfhi2f(v0.w);
  }
  u32x4 o;
  o.x = (unsigned)f2bf(a0) | ((unsigned)f2bf(a1) << 16);
  o.y = (unsigned)f2bf(a2) | ((unsigned)f2bf(a3) << 16);
  o.z = (unsigned)f2bf(a4) | ((unsigned)f2bf(a5) << 16);
  o.w = (unsigned)f2bf(a6) | ((unsigned)f2bf(a7) << 16);
  ((u32x4*)(Gcat + (size_t)node * KK + t * DD))[sub] = o;
}

// ---------------- bf16 MFMA GEMM: C = relu(Gcat[M][768] @ WT^T), N=256 ----------------
// BM=128, BN=256 (A read ONCE), 512 threads = 8 waves (2Mx4N), wave tile 64x64.
// Single 48KB LDS (A 16KB | B 32KB), XOR-swizzled; reg-prefetch next kt before
// compute; 2 barriers per kt. __launch_bounds__(512,4): cap VGPR at 128 so TWO
// 8-wave blocks co-reside per CU (r11 ran 1 block/CU; the co-resident block
// hides the vmcnt(0) drain at SWRITE).
template <int OUTF32>
__global__ __launch_bounds__(512, 4) void gemm_bf16(const unsigned short* __restrict__ A,
                                                    const unsigned short* __restrict__ BT,
                                                    void* __restrict__ Cout) {
  __shared__ __align__(16) char lds[49152];  // [A 16KB | B 32KB]
  const int tid = threadIdx.x;
  const int w = tid >> 6, lane = tid & 63;
  const int m0 = blockIdx.x * 128;
  const int wm = (w >> 2) * 64, wn = (w & 3) * 64;
  const int r15 = lane & 15;
  const int g16 = (lane >> 4) * 16;  // byte offset of k-subgroup (8 bf16)

  f32x4 acc[4][4] = {};
  const char* Ab = (const char*)A;
  const char* Bb = (const char*)BT;

  // A staging: 512 thr x 32B: arow = tid>>2 (0..127), acol = (tid&3)*32
  const int arow = tid >> 2;
  const int acol = (tid & 3) * 32;
  const int asw = (arow & 7) << 4;
  // B staging: 512 thr x 64B: brow = tid>>1 (0..255), bcol = (tid&1)*64
  const int brow = tid >> 1;
  const int bcol = (tid & 1) * 64;
  const int bsw = (brow & 7) << 4;
  u32x4 ra[2], rb[4];

  const int NTK = KK / 64;  // 12

#define GLOAD(kt)                                                            \
  {                                                                          \
    const char* ap = Ab + (size_t)(m0 + arow) * (KK * 2) + (size_t)(kt)*128; \
    const char* bp = Bb + (size_t)brow * (KK * 2) + (size_t)(kt)*128;        \
    ra[0] = *(const u32x4*)(ap + acol);                                      \
    ra[1] = *(const u32x4*)(ap + acol + 16);                                 \
    _Pragma("unroll") for (int p = 0; p < 4; p++) rb[p] =                    \
        *(const u32x4*)(bp + bcol + p * 16);                                 \
  }
#define SWRITE()                                                             \
  {                                                                          \
    *(u32x4*)(lds + arow * 128 + (acol ^ asw)) = ra[0];                      \
    *(u32x4*)(lds + arow * 128 + ((acol + 16) ^ asw)) = ra[1];               \
    _Pragma("unroll") for (int p = 0; p < 4; p++) *(u32x4*)(                 \
        lds + 16384 + brow * 128 + ((bcol + p * 16) ^ bsw)) = rb[p];         \
  }

  GLOAD(0);
  SWRITE();
  __syncthreads();
  for (int kt = 0; kt < NTK; ++kt) {
    if (kt + 1 < NTK) GLOAD(kt + 1);  // issue next-tile loads before compute
#pragma unroll
    for (int ks = 0; ks < 2; ++ks) {
      bf16x8 af[4], bfr[4];
#pragma unroll
      for (int mf = 0; mf < 4; ++mf) {
        int row = wm + mf * 16 + r15;
        af[mf] = *(const bf16x8*)(lds + row * 128 + ((ks * 64 + g16) ^ ((row & 7) << 4)));
      }
#pragma unroll
      for (int nf = 0; nf < 4; ++nf) {
        int row = wn + nf * 16 + r15;
        bfr[nf] =
            *(const bf16x8*)(lds + 16384 + row * 128 + ((ks * 64 + g16) ^ ((row & 7) << 4)));
      }
#pragma unroll
      for (int mf = 0; mf < 4; ++mf)
#pragma unroll
        for (int nf = 0; nf < 4; ++nf)
          acc[mf][nf] =
              __builtin_amdgcn_mfma_f32_16x16x32_bf16(af[mf], bfr[nf], acc[mf][nf], 0, 0, 0);
    }
    if (kt + 1 < NTK) {
      __syncthreads();  // all waves done reading this tile
      SWRITE();         // overwrite with prefetched next tile
      __syncthreads();  // writes visible
    }
  }

  // epilogue: D row = (lane>>4)*4 + reg, col = lane&15 (verified m89 layout); ReLU
#pragma unroll
  for (int mf = 0; mf < 4; ++mf) {
#pragma unroll
    for (int r = 0; r < 4; ++r) {
      int grow = m0 + wm + mf * 16 + (lane >> 4) * 4 + r;
      if (grow >= NN) continue;
#pragma unroll
      for (int nf = 0; nf < 4; ++nf) {
        int gcol = wn + nf * 16 + r15;
        float v = fmaxf(acc[mf][nf][r], 0.f);
        if (OUTF32)
          ((float*)Cout)[(size_t)grow * DD + gcol] = v;
        else
          ((unsigned short*)Cout)[(size_t)grow * DD + gcol] = f2bf(v);
      }
    }
  }
#undef GLOAD
#undef SWRITE
}

extern "C" void kernel_launch(void* const* d_in, const int* in_sizes, int n_in,
                              void* d_out, int out_size, void* d_ws, size_t ws_size,
                              hipStream_t stream) {
  const int* labels = (const int*)d_in[0];
  const int* adj = (const int*)d_in[1];      // [NT][EPT][2]
  const float* emb = (const float*)d_in[2];  // [VOCAB][DD]
  const float* Wl = (const float*)d_in[3];   // [NL][NT][DD][DD]

  // ---- workspace layout (~108.3 MB) ----
  char* base = (char*)d_ws;
  unsigned short* h = (unsigned short*)base;  // bf16 [NN][256], 25.6 MB
  size_t off = (size_t)NN * DD * 2;
  unsigned short* Gcat = (unsigned short*)(base + off);  // bf16 [MROWS][768], 76.9 MB
  off += (size_t)MROWS * KK * 2;
  unsigned short* WT = (unsigned short*)(base + off);  // bf16 [NL][256][768], 1.57 MB
  off += (size_t)NL * DD * KK * 2;
  int* rowptr = (int*)(base + off);  // [NT][NN+1]
  off += (size_t)((NT * (NN + 1) * 4 + 15) & ~15);
  int* esrc = (int*)(base + off);  // [NT][EPT]

  // CSR-build temporaries overlaid on Gcat (not live until first agg)
  int* counts = (int*)Gcat;                       // 3*NN ints
  int* cursor = (int*)((char*)Gcat + (1 << 20));  // +1MB
  int* bsums = (int*)((char*)Gcat + (2 << 20));   // +2MB

  // ---- weight convert + h0 gather ----
  wconv<<<(NL * DD * KK) / 256, 256, 0, stream>>>(Wl, WT);
  gather_emb<<<NN, 64, 0, stream>>>(labels, emb, h);

  // ---- CSR build (once; adjacency shared by all layers) ----
  zero_kernel<<<256, 256, 0, stream>>>((float*)counts, (3 * NN) / 4);
  {
    dim3 g((EPT + 255) / 256, NT);
    hist_kernel<<<g, 256, 0, stream>>>(adj, counts);
  }
  {
    dim3 g(SCAN_BLOCKS, NT);
    scan1<<<g, 256, 0, stream>>>(counts, rowptr, bsums);
  }
  scan2<<<NT, 256, 0, stream>>>(bsums);
  {
    dim3 g(SCAN_BLOCKS, NT);
    scan3<<<g, 256, 0, stream>>>(rowptr, bsums, cursor);
  }
  {
    dim3 g((EPT + 255) / 256, NT);
    bucket_kernel<<<g, 256, 0, stream>>>(adj, cursor, esrc);
  }

  // ---- layers: agg (all 3 types, one dispatch) then one K=768 GEMM ----
  dim3 ga((NN + 7) / 8, NT);
  const int gg = MROWS / 128;  // 391 blocks, full-N per block
  for (int l = 0; l < NL; ++l) {
    agg_csr<<<ga, 256, 0, stream>>>(rowptr, esrc, h, Gcat);
    const unsigned short* WTl = WT + (size_t)l * DD * KK;
    if (l < NL - 1)
      gemm_bf16<0><<<gg, 512, 0, stream>>>(Gcat, WTl, h);
    else
      gemm_bf16<1><<<gg, 512, 0, stream>>>(Gcat, WTl, d_out);
  }
}

// Round 14
// 502.087 us; speedup vs baseline: 1.3759x; 1.0311x over previous
//
#include <hip/hip_runtime.h>

#define NN 50000
#define DD 256
#define NT 3
#define NL 4
#define EPT 300000
#define KK 768           // 3*DD concatenated-K
#define SCAN_BLOCKS 196  // ceil(50000/256)
#define MROWS 50048      // Gcat rows padded to 128

typedef __attribute__((ext_vector_type(8))) short bf16x8;
typedef __attribute__((ext_vector_type(4))) float f32x4;
typedef __attribute__((ext_vector_type(4))) unsigned int u32x4;

__device__ __forceinline__ unsigned short f2bf(float f) {
  unsigned u = __builtin_bit_cast(unsigned, f);
  unsigned r = u + 0x7fffu + ((u >> 16) & 1u);  // RNE
  return (unsigned short)(r >> 16);
}
__device__ __forceinline__ float bflo2f(unsigned u) {
  return __builtin_bit_cast(float, u << 16);
}
__device__ __forceinline__ float bfhi2f(unsigned u) {
  return __builtin_bit_cast(float, u & 0xffff0000u);
}

// ---------------- h0[i] = bf16(emb[labels[i]]) ----------------
__global__ void gather_emb(const int* __restrict__ labels,
                           const float* __restrict__ emb,
                           unsigned short* __restrict__ h) {
  int node = blockIdx.x;
  int lane = threadIdx.x;  // 0..63
  float4 v = ((const float4*)(emb + (size_t)labels[node] * DD))[lane];
  unsigned a = (unsigned)f2bf(v.x) | ((unsigned)f2bf(v.y) << 16);
  unsigned b = (unsigned)f2bf(v.z) | ((unsigned)f2bf(v.w) << 16);
  ((uint2*)(h + (size_t)node * DD))[lane] = make_uint2(a, b);
}

// ---------------- zero buffer ----------------
__global__ void zero_kernel(float* __restrict__ p, int n4) {
  int i = blockIdx.x * blockDim.x + threadIdx.x;
  int stride = gridDim.x * blockDim.x;
  float4* p4 = (float4*)p;
  for (; i < n4; i += stride) p4[i] = make_float4(0.f, 0.f, 0.f, 0.f);
}

// ---- W -> bf16, transposed+concatenated AND pre-swizzled for global_load_lds ----
// WT[l][n][ kk ^ ((n&7)<<3) ] = W[l][t][k][n]  (16B-chunk XOR within each 128B span)
__global__ __launch_bounds__(256) void wconv(const float* __restrict__ Wl,
                                             unsigned short* __restrict__ WT) {
  int i = blockIdx.x * 256 + threadIdx.x;
  int l = i / (DD * KK);
  int rem = i % (DD * KK);
  int n = rem / KK;
  int kk = rem % KK;
  int t = kk >> 8;
  int k = kk & 255;
  float v = Wl[((size_t)(l * NT + t) * DD + k) * DD + n];
  WT[(size_t)l * DD * KK + (size_t)n * KK + (kk ^ ((n & 7) << 3))] = f2bf(v);
}

// ---------------- CSR build ----------------
__global__ __launch_bounds__(256) void hist_kernel(const int* __restrict__ adj,
                                                   int* __restrict__ counts) {
  int t = blockIdx.y;
  int e = blockIdx.x * 256 + threadIdx.x;
  if (e >= EPT) return;
  int tgt = adj[(size_t)t * EPT * 2 + 2 * e + 1];
  atomicAdd(&counts[t * NN + tgt], 1);
}

__global__ __launch_bounds__(256) void scan1(const int* __restrict__ counts,
                                             int* __restrict__ rowptr,
                                             int* __restrict__ bsums) {
  int t = blockIdx.y, b = blockIdx.x;
  int i = b * 256 + threadIdx.x;
  int v = (i < NN) ? counts[t * NN + i] : 0;
  __shared__ int s[256];
  s[threadIdx.x] = v;
  __syncthreads();
  for (int off = 1; off < 256; off <<= 1) {
    int y = (threadIdx.x >= off) ? s[threadIdx.x - off] : 0;
    __syncthreads();
    s[threadIdx.x] += y;
    __syncthreads();
  }
  if (i < NN) rowptr[t * (NN + 1) + i] = s[threadIdx.x] - v;  // exclusive
  if (threadIdx.x == 255) bsums[t * SCAN_BLOCKS + b] = s[255];
}

__global__ __launch_bounds__(256) void scan2(int* __restrict__ bsums) {
  int t = blockIdx.x;
  int v = (threadIdx.x < SCAN_BLOCKS) ? bsums[t * SCAN_BLOCKS + threadIdx.x] : 0;
  __shared__ int s[256];
  s[threadIdx.x] = v;
  __syncthreads();
  for (int off = 1; off < 256; off <<= 1) {
    int y = (threadIdx.x >= off) ? s[threadIdx.x - off] : 0;
    __syncthreads();
    s[threadIdx.x] += y;
    __syncthreads();
  }
  if (threadIdx.x < SCAN_BLOCKS) bsums[t * SCAN_BLOCKS + threadIdx.x] = s[threadIdx.x] - v;
}

__global__ __launch_bounds__(256) void scan3(int* __restrict__ rowptr,
                                             const int* __restrict__ bsums,
                                             int* __restrict__ cursor) {
  int t = blockIdx.y, b = blockIdx.x;
  int i = b * 256 + threadIdx.x;
  if (i < NN) {
    int r = rowptr[t * (NN + 1) + i] + bsums[t * SCAN_BLOCKS + b];
    rowptr[t * (NN + 1) + i] = r;
    cursor[t * NN + i] = r;
  }
  if (b == 0 && threadIdx.x == 0) rowptr[t * (NN + 1) + NN] = EPT;
}

__global__ __launch_bounds__(256) void bucket_kernel(const int* __restrict__ adj,
                                                     int* __restrict__ cursor,
                                                     int* __restrict__ esrc) {
  int t = blockIdx.y;
  int e = blockIdx.x * 256 + threadIdx.x;
  if (e >= EPT) return;
  int s = adj[(size_t)t * EPT * 2 + 2 * e];
  int tgt = adj[(size_t)t * EPT * 2 + 2 * e + 1];
  int pos = atomicAdd(&cursor[t * NN + tgt], 1);
  esrc[(size_t)t * EPT + pos] = s;
}

// ---------------- agg: Gcat (PRE-SWIZZLED) = bf16( sum_{e in(n)} h[src(e)] ) ----------------
// 2 nodes per wave: 32 lanes x 16B; unroll 4 (r11-proven). The 16B output chunk
// is written at sub ^ (node&7) so the GEMM's linear global_load_lds yields the
// bank-conflict-free XOR-swizzled LDS layout (both-sides-or-neither rule).
__global__ __launch_bounds__(256) void agg_csr(const int* __restrict__ rowptr,
                                               const int* __restrict__ esrc,
                                               const unsigned short* __restrict__ h,
                                               unsigned short* __restrict__ Gcat) {
  int t = blockIdx.y;
  int node = blockIdx.x * 8 + (threadIdx.x >> 5);
  if (node >= NN) return;
  int sub = threadIdx.x & 31;
  const int* rp = rowptr + t * (NN + 1);
  const int* es = esrc + (size_t)t * EPT;
  int e = rp[node];
  int end = rp[node + 1];
  const u32x4* h4 = (const u32x4*)h;
  float a0 = 0.f, a1 = 0.f, a2 = 0.f, a3 = 0.f, a4 = 0.f, a5 = 0.f, a6 = 0.f, a7 = 0.f;
  for (; e + 3 < end; e += 4) {
    u32x4 v0 = h4[(size_t)es[e] * 32 + sub];
    u32x4 v1 = h4[(size_t)es[e + 1] * 32 + sub];
    u32x4 v2 = h4[(size_t)es[e + 2] * 32 + sub];
    u32x4 v3 = h4[(size_t)es[e + 3] * 32 + sub];
    a0 += (bflo2f(v0.x) + bflo2f(v1.x)) + (bflo2f(v2.x) + bflo2f(v3.x));
    a1 += (bfhi2f(v0.x) + bfhi2f(v1.x)) + (bfhi2f(v2.x) + bfhi2f(v3.x));
    a2 += (bflo2f(v0.y) + bflo2f(v1.y)) + (bflo2f(v2.y) + bflo2f(v3.y));
    a3 += (bfhi2f(v0.y) + bfhi2f(v1.y)) + (bfhi2f(v2.y) + bfhi2f(v3.y));
    a4 += (bflo2f(v0.z) + bflo2f(v1.z)) + (bflo2f(v2.z) + bflo2f(v3.z));
    a5 += (bfhi2f(v0.z) + bfhi2f(v1.z)) + (bfhi2f(v2.z) + bfhi2f(v3.z));
    a6 += (bflo2f(v0.w) + bflo2f(v1.w)) + (bflo2f(v2.w) + bflo2f(v3.w));
    a7 += (bfhi2f(v0.w) + bfhi2f(v1.w)) + (bfhi2f(v2.w) + bfhi2f(v3.w));
  }
  for (; e < end; ++e) {
    u32x4 v0 = h4[(size_t)es[e] * 32 + sub];
    a0 += bflo2f(v0.x);
    a1 += bfhi2f(v0.x);
    a2 += bflo2f(v0.y);
    a3 += bfhi2f(v0.y);
    a4 += bflo2f(v0.z);
    a5 += bfhi2f(v0.z);
    a6 += bflo2f(v0.w);
    a7 += bfhi2f(v0.w);
  }
  u32x4 o;
  o.x = (unsigned)f2bf(a0) | ((unsigned)f2bf(a1) << 16);
  o.y = (unsigned)f2bf(a2) | ((unsigned)f2bf(a3) << 16);
  o.z = (unsigned)f2bf(a4) | ((unsigned)f2bf(a5) << 16);
  o.w = (unsigned)f2bf(a6) | ((unsigned)f2bf(a7) << 16);
  ((u32x4*)(Gcat + (size_t)node * KK + t * DD))[sub ^ (node & 7)] = o;
}

// ---------------- bf16 MFMA GEMM: C = relu(Gcat[M][768] @ WT^T), N=256 ----------------
// BM=128, BN=256 (A read ONCE), 512 threads = 8 waves (2Mx4N), wave tile 64x64.
// Staging via global_load_lds dwordx4 (linear LDS dest; sources pre-swizzled by
// agg/wconv so ds_read keeps the conflict-free XOR layout). Single 48KB buffer,
// 2 barriers per kt; co-resident block hides the load drain.
#define GLL(g, l)                                                     \
  __builtin_amdgcn_global_load_lds(                                   \
      (const __attribute__((address_space(1))) unsigned int*)(g),     \
      (__attribute__((address_space(3))) unsigned int*)(l), 16, 0, 0)

template <int OUTF32>
__global__ __launch_bounds__(512, 4) void gemm_bf16(const unsigned short* __restrict__ A,
                                                    const unsigned short* __restrict__ BT,
                                                    void* __restrict__ Cout) {
  __shared__ __align__(16) char lds[49152];  // [A 16KB | B 32KB]
  const int tid = threadIdx.x;
  const int w = tid >> 6, lane = tid & 63;
  const int m0 = blockIdx.x * 128;
  const int wm = (w >> 2) * 64, wn = (w & 3) * 64;
  const int r15 = lane & 15;
  const int g16 = (lane >> 4) * 16;  // byte offset of k-subgroup (8 bf16)

  f32x4 acc[4][4] = {};
  const char* Ab = (const char*)A;
  const char* Bb = (const char*)BT;

  // per-lane global source offsets for the linear 1KB wave copies
  const int lrow = lane >> 3;          // 0..7
  const int lcol = (lane & 7) * 16;    // 0..112

  const int NTK = KK / 64;  // 12

#define LOADTILE(kt)                                                                   \
  {                                                                                    \
    _Pragma("unroll") for (int i = 0; i < 2; ++i) {                                    \
      const char* g =                                                                  \
          Ab + (size_t)(m0 + w * 16 + i * 8 + lrow) * (KK * 2) + (size_t)(kt)*128 + lcol; \
      GLL(g, lds + (w * 16 + i * 8) * 128);                                            \
    }                                                                                  \
    _Pragma("unroll") for (int j = 0; j < 4; ++j) {                                    \
      const char* g =                                                                  \
          Bb + (size_t)(w * 32 + j * 8 + lrow) * (KK * 2) + (size_t)(kt)*128 + lcol;   \
      GLL(g, lds + 16384 + (w * 32 + j * 8) * 128);                                    \
    }                                                                                  \
  }

  LOADTILE(0);
  __syncthreads();  // drains vmcnt: tile 0 resident
  for (int kt = 0; kt < NTK; ++kt) {
#pragma unroll
    for (int ks = 0; ks < 2; ++ks) {
      bf16x8 af[4], bfr[4];
#pragma unroll
      for (int mf = 0; mf < 4; ++mf) {
        int row = wm + mf * 16 + r15;
        af[mf] = *(const bf16x8*)(lds + row * 128 + ((ks * 64 + g16) ^ ((row & 7) << 4)));
      }
#pragma unroll
      for (int nf = 0; nf < 4; ++nf) {
        int row = wn + nf * 16 + r15;
        bfr[nf] =
            *(const bf16x8*)(lds + 16384 + row * 128 + ((ks * 64 + g16) ^ ((row & 7) << 4)));
      }
#pragma unroll
      for (int mf = 0; mf < 4; ++mf)
#pragma unroll
        for (int nf = 0; nf < 4; ++nf)
          acc[mf][nf] =
              __builtin_amdgcn_mfma_f32_16x16x32_bf16(af[mf], bfr[nf], acc[mf][nf], 0, 0, 0);
    }
    if (kt + 1 < NTK) {
      __syncthreads();      // all waves done reading this tile
      LOADTILE(kt + 1);     // linear DMA into the single buffer
      __syncthreads();      // vmcnt(0) drain + visibility
    }
  }

  // epilogue: D row = (lane>>4)*4 + reg, col = lane&15 (verified m89 layout); ReLU
#pragma unroll
  for (int mf = 0; mf < 4; ++mf) {
#pragma unroll
    for (int r = 0; r < 4; ++r) {
      int grow = m0 + wm + mf * 16 + (lane >> 4) * 4 + r;
      if (grow >= NN) continue;
#pragma unroll
      for (int nf = 0; nf < 4; ++nf) {
        int gcol = wn + nf * 16 + r15;
        float v = fmaxf(acc[mf][nf][r], 0.f);
        if (OUTF32)
          ((float*)Cout)[(size_t)grow * DD + gcol] = v;
        else
          ((unsigned short*)Cout)[(size_t)grow * DD + gcol] = f2bf(v);
      }
    }
  }
#undef LOADTILE
}

extern "C" void kernel_launch(void* const* d_in, const int* in_sizes, int n_in,
                              void* d_out, int out_size, void* d_ws, size_t ws_size,
                              hipStream_t stream) {
  const int* labels = (const int*)d_in[0];
  const int* adj = (const int*)d_in[1];      // [NT][EPT][2]
  const float* emb = (const float*)d_in[2];  // [VOCAB][DD]
  const float* Wl = (const float*)d_in[3];   // [NL][NT][DD][DD]

  // ---- workspace layout (~108.3 MB) ----
  char* base = (char*)d_ws;
  unsigned short* h = (unsigned short*)base;  // bf16 [NN][256], 25.6 MB
  size_t off = (size_t)NN * DD * 2;
  unsigned short* Gcat = (unsigned short*)(base + off);  // bf16 [MROWS][768] (pre-swizzled)
  off += (size_t)MROWS * KK * 2;
  unsigned short* WT = (unsigned short*)(base + off);  // bf16 [NL][256][768] (pre-swizzled)
  off += (size_t)NL * DD * KK * 2;
  int* rowptr = (int*)(base + off);  // [NT][NN+1]
  off += (size_t)((NT * (NN + 1) * 4 + 15) & ~15);
  int* esrc = (int*)(base + off);  // [NT][EPT]

  // CSR-build temporaries overlaid on Gcat (not live until first agg)
  int* counts = (int*)Gcat;                       // 3*NN ints
  int* cursor = (int*)((char*)Gcat + (1 << 20));  // +1MB
  int* bsums = (int*)((char*)Gcat + (2 << 20));   // +2MB

  // ---- weight convert + h0 gather ----
  wconv<<<(NL * DD * KK) / 256, 256, 0, stream>>>(Wl, WT);
  gather_emb<<<NN, 64, 0, stream>>>(labels, emb, h);

  // ---- CSR build (once; adjacency shared by all layers) ----
  zero_kernel<<<256, 256, 0, stream>>>((float*)counts, (3 * NN) / 4);
  {
    dim3 g((EPT + 255) / 256, NT);
    hist_kernel<<<g, 256, 0, stream>>>(adj, counts);
  }
  {
    dim3 g(SCAN_BLOCKS, NT);
    scan1<<<g, 256, 0, stream>>>(counts, rowptr, bsums);
  }
  scan2<<<NT, 256, 0, stream>>>(bsums);
  {
    dim3 g(SCAN_BLOCKS, NT);
    scan3<<<g, 256, 0, stream>>>(rowptr, bsums, cursor);
  }
  {
    dim3 g((EPT + 255) / 256, NT);
    bucket_kernel<<<g, 256, 0, stream>>>(adj, cursor, esrc);
  }

  // ---- layers: agg (all 3 types, one dispatch) then one K=768 GEMM ----
  dim3 ga((NN + 7) / 8, NT);
  const int gg = MROWS / 128;  // 391 blocks, full-N per block
  for (int l = 0; l < NL; ++l) {
    agg_csr<<<ga, 256, 0, stream>>>(rowptr, esrc, h, Gcat);
    const unsigned short* WTl = WT + (size_t)l * DD * KK;
    if (l < NL - 1)
      gemm_bf16<0><<<gg, 512, 0, stream>>>(Gcat, WTl, h);
    else
      gemm_bf16<1><<<gg, 512, 0, stream>>>(Gcat, WTl, d_out);
  }
}